// Round 1
// baseline (357.341 us; speedup 1.0000x reference)
//
#include <hip/hip_runtime.h>
#include <hip/hip_bf16.h>
#include <stdint.h>
#include <stddef.h>

typedef __bf16 bf16;
typedef __bf16 bf16x8 __attribute__((ext_vector_type(8)));
typedef float f32x4 __attribute__((ext_vector_type(4)));

#define NB 4
#define SEQ 2048
#define MD 1024
#define NH 16
#define HDIM 64

// ---------------- helpers ----------------

__device__ __forceinline__ void gload16(const void* g, void* lds) {
  __builtin_amdgcn_global_load_lds(
      (const __attribute__((address_space(1))) unsigned int*)(uintptr_t)g,
      (__attribute__((address_space(3))) unsigned int*)(unsigned int)(uintptr_t)lds,
      16, 0, 0);
}

// rows are 64 bf16 = 128B. slot = 16B chunk index [0,8). XOR-swizzled.
__device__ __forceinline__ bf16x8 lds_read8(const bf16* base, int row, int slot) {
  const char* p = (const char*)base + row * 128 + ((slot ^ (row & 7)) << 4);
  return *(const bf16x8*)p;
}

// ---------------- kernel 1: embedded fp32 -> bf16 ----------------

__global__ void k_cvt_embed(const float* __restrict__ src, bf16* __restrict__ dst) {
  int i = blockIdx.x * blockDim.x + threadIdx.x;   // 1,048,576 threads, 8 elems each
  const float4* s4 = (const float4*)src;
  float4 a = s4[2 * i], b = s4[2 * i + 1];
  bf16x8 v;
  v[0] = (bf16)a.x; v[1] = (bf16)a.y; v[2] = (bf16)a.z; v[3] = (bf16)a.w;
  v[4] = (bf16)b.x; v[5] = (bf16)b.y; v[6] = (bf16)b.z; v[7] = (bf16)b.w;
  ((bf16x8*)dst)[i] = v;
}

// ---------------- kernel 2: weights -> bf16 (QKV transposed to B^T) --------
// WT[h][r][d]  (r: 0..63 Q-e, 64..127 K-e, 128..191 V-e)  = W{q,k,v}[h][d][e]
// WoB[n][d] = Wo[n][d]

__global__ void k_cvt_w(const float* __restrict__ Wq, const float* __restrict__ Wk,
                        const float* __restrict__ Wv, const float* __restrict__ Wo,
                        bf16* __restrict__ WT, bf16* __restrict__ WoB) {
  int i = blockIdx.x * blockDim.x + threadIdx.x;   // 4,194,304 threads
  if (i < 16 * 192 * 1024) {
    int h = i / (192 * 1024);
    int rem = i - h * (192 * 1024);
    int r = rem >> 10;
    int d = rem & 1023;
    const float* W = (r < 64) ? Wq : (r < 128 ? Wk : Wv);
    int e = r & 63;
    WT[i] = (bf16)W[h * 65536 + d * 64 + e];
  } else {
    int j = i - 16 * 192 * 1024;                   // 0..1048575
    WoB[j] = (bf16)Wo[j];
  }
}

// ---------------- kernel 3: QKV projection GEMM ----------------
// C[8192 x 192] per head; A = E bf16 [8192][1024]; B^T = WT[h] [192][1024]

__launch_bounds__(256, 2)
__global__ void k_qkv(const bf16* __restrict__ E, const bf16* __restrict__ WT,
                      bf16* __restrict__ Qo, bf16* __restrict__ Ko, bf16* __restrict__ Vo) {
  __shared__ __align__(16) bf16 As[128 * 64];
  __shared__ __align__(16) bf16 Bs[192 * 64];
  const int h = blockIdx.y;
  const int m0 = blockIdx.x * 128;
  const int tid = threadIdx.x;
  const int w = tid >> 6, lane = tid & 63;
  const int wm = w >> 1, wn = w & 1;               // 2x2 waves -> wave tile 64x96
  const int cl = lane & 15, g4 = lane >> 4;
  const int srow = lane >> 3;
  const int scol = ((lane & 7) ^ (lane >> 3)) << 3; // pre-swizzled source col (elems)
  const bf16* Wh = WT + (size_t)h * 192 * 1024;
  f32x4 zero = {0.f, 0.f, 0.f, 0.f};
  f32x4 acc[4][6];
#pragma unroll
  for (int m = 0; m < 4; ++m)
#pragma unroll
    for (int n = 0; n < 6; ++n) acc[m][n] = zero;

  for (int kt = 0; kt < 16; ++kt) {
    const int k0 = kt * 64;
    __syncthreads();
#pragma unroll
    for (int c = 0; c < 4; ++c) {                   // A: 16 chunks of 1KB
      int cc = w * 4 + c;
      gload16(E + (size_t)(m0 + cc * 8 + srow) * 1024 + k0 + scol, (char*)As + cc * 1024);
    }
#pragma unroll
    for (int c = 0; c < 6; ++c) {                   // B: 24 chunks
      int cc = w * 6 + c;
      gload16(Wh + (size_t)(cc * 8 + srow) * 1024 + k0 + scol, (char*)Bs + cc * 1024);
    }
    __syncthreads();
#pragma unroll
    for (int kk = 0; kk < 2; ++kk) {
      bf16x8 a[4], b[6];
#pragma unroll
      for (int m = 0; m < 4; ++m) a[m] = lds_read8(As, wm * 64 + m * 16 + cl, kk * 4 + g4);
#pragma unroll
      for (int n = 0; n < 6; ++n) b[n] = lds_read8(Bs, wn * 96 + n * 16 + cl, kk * 4 + g4);
#pragma unroll
      for (int m = 0; m < 4; ++m)
#pragma unroll
        for (int n = 0; n < 6; ++n)
          acc[m][n] = __builtin_amdgcn_mfma_f32_16x16x32_bf16(a[m], b[n], acc[m][n], 0, 0, 0);
    }
  }
  // epilogue: scatter to Q/K/V [b][h][s][64] bf16
#pragma unroll
  for (int n = 0; n < 6; ++n) {
    int ncol = wn * 96 + n * 16 + cl;               // 0..191
    int which = ncol >> 6, e = ncol & 63;
    bf16* dst = which == 0 ? Qo : (which == 1 ? Ko : Vo);
#pragma unroll
    for (int m = 0; m < 4; ++m) {
#pragma unroll
      for (int r = 0; r < 4; ++r) {
        int row = m0 + wm * 64 + m * 16 + g4 * 4 + r;   // 0..8191
        int bb = row >> 11, ss = row & 2047;
        dst[(((size_t)(bb * 16 + h) * 2048 + ss) << 6) + e] = (bf16)acc[m][n][r];
      }
    }
  }
}

// ---------------- kernel 4: causal flash attention ----------------
// grid (32 q-tiles, 64 bh); 4 waves x 16 q-rows; KBLK=64; HD=64

__launch_bounds__(256, 2)
__global__ void k_attn(const bf16* __restrict__ Qg, const bf16* __restrict__ Kg,
                       const bf16* __restrict__ Vg, bf16* __restrict__ CTX) {
  __shared__ __align__(16) bf16 Ks[64 * 64];
  __shared__ __align__(16) bf16 Vt[64 * 64];    // transposed: [d][key], swizzled
  __shared__ __align__(16) bf16 Ps[4 * 16 * 64];
  const int qt = blockIdx.x;
  const int bh = blockIdx.y;
  const int q0 = qt * 64;
  const int tid = threadIdx.x, w = tid >> 6, lane = tid & 63;
  const int cl = lane & 15, g4 = lane >> 4;
  const bf16* Qb = Qg + (size_t)bh * 2048 * 64;
  const bf16* Kb = Kg + (size_t)bh * 2048 * 64;
  const bf16* Vb = Vg + (size_t)bh * 2048 * 64;
  const float CSC = 0.125f * 1.44269504089f;    // 1/sqrt(64) * log2(e)

  // Q fragments held in registers for all kv iterations
  bf16x8 qa[2];
  {
    int qrow = q0 + w * 16 + cl;
    qa[0] = *(const bf16x8*)(Qb + (size_t)qrow * 64 + g4 * 8);
    qa[1] = *(const bf16x8*)(Qb + (size_t)qrow * 64 + 32 + g4 * 8);
  }
  f32x4 zero = {0.f, 0.f, 0.f, 0.f};
  f32x4 o[4];
#pragma unroll
  for (int i = 0; i < 4; ++i) o[i] = zero;
  float mr[4], ls[4];
#pragma unroll
  for (int r = 0; r < 4; ++r) { mr[r] = -__builtin_inff(); ls[r] = 0.f; }

  for (int kv = 0; kv <= qt; ++kv) {
    const int kv0 = kv * 64;
    __syncthreads();
    // stage K tile (swizzled via pre-swizzled source)
    {
      int scol = ((lane & 7) ^ (lane >> 3)) << 3;
#pragma unroll
      for (int c = 0; c < 2; ++c) {
        int cc = w * 2 + c;
        gload16(Kb + (size_t)(kv0 + cc * 8 + (lane >> 3)) * 64 + scol, (char*)Ks + cc * 1024);
      }
    }
    // stage V transposed (reg-staged, swizzled scalar writes)
    {
      int key = tid >> 2, d0 = (tid & 3) << 4;
      const bf16* g = Vb + (size_t)(kv0 + key) * 64 + d0;
      bf16x8 v0 = *(const bf16x8*)g;
      bf16x8 v1 = *(const bf16x8*)(g + 8);
#pragma unroll
      for (int j = 0; j < 8; ++j) {
        int dd = d0 + j;
        *(bf16*)((char*)Vt + ((dd * 128 + key * 2) ^ ((dd & 7) << 4))) = v0[j];
        dd = d0 + 8 + j;
        *(bf16*)((char*)Vt + ((dd * 128 + key * 2) ^ ((dd & 7) << 4))) = v1[j];
      }
    }
    __syncthreads();

    // S = Q K^T  (per wave: 16 q-rows x 64 keys)
    f32x4 s[4];
#pragma unroll
    for (int nt = 0; nt < 4; ++nt) s[nt] = zero;
#pragma unroll
    for (int kk = 0; kk < 2; ++kk) {
#pragma unroll
      for (int nt = 0; nt < 4; ++nt) {
        bf16x8 kb = lds_read8(Ks, nt * 16 + cl, kk * 4 + g4);
        s[nt] = __builtin_amdgcn_mfma_f32_16x16x32_bf16(qa[kk], kb, s[nt], 0, 0, 0);
      }
    }

    // scale (+ causal mask on diagonal tile), exp2 domain
    const bool diag = (kv == qt);
    float t[4][4];
#pragma unroll
    for (int nt = 0; nt < 4; ++nt)
#pragma unroll
      for (int r = 0; r < 4; ++r) {
        float v = s[nt][r] * CSC;
        if (diag && (nt * 16 + cl) > (w * 16 + g4 * 4 + r)) v = -__builtin_inff();
        t[nt][r] = v;
      }

    // online softmax per row (lane's 4 rows; 16-lane group covers cols)
#pragma unroll
    for (int r = 0; r < 4; ++r) {
      float mx = fmaxf(fmaxf(t[0][r], t[1][r]), fmaxf(t[2][r], t[3][r]));
      mx = fmaxf(mx, __shfl_xor(mx, 1));
      mx = fmaxf(mx, __shfl_xor(mx, 2));
      mx = fmaxf(mx, __shfl_xor(mx, 4));
      mx = fmaxf(mx, __shfl_xor(mx, 8));
      float mnew = fmaxf(mr[r], mx);
      float al = exp2f(mr[r] - mnew);
      mr[r] = mnew;
      float psum = 0.f;
#pragma unroll
      for (int nt = 0; nt < 4; ++nt) {
        float p = exp2f(t[nt][r] - mnew);
        t[nt][r] = p;
        psum += p;
      }
      psum += __shfl_xor(psum, 1);
      psum += __shfl_xor(psum, 2);
      psum += __shfl_xor(psum, 4);
      psum += __shfl_xor(psum, 8);
      ls[r] = ls[r] * al + psum;
#pragma unroll
      for (int nt2 = 0; nt2 < 4; ++nt2) o[nt2][r] *= al;
    }

    // P -> wave-private LDS (D-frag layout -> A-frag layout)
    bf16* Pw = (bf16*)Ps + w * 1024;
#pragma unroll
    for (int nt = 0; nt < 4; ++nt)
#pragma unroll
      for (int r = 0; r < 4; ++r) {
        int prow = g4 * 4 + r, pkey = nt * 16 + cl;
        *(bf16*)((char*)Pw + ((prow * 128 + pkey * 2) ^ ((prow & 7) << 4))) = (bf16)t[nt][r];
      }

    // O += P V
#pragma unroll
    for (int kc = 0; kc < 2; ++kc) {
      bf16x8 pa = lds_read8(Pw, cl, kc * 4 + g4);
#pragma unroll
      for (int nt2 = 0; nt2 < 4; ++nt2) {
        bf16x8 vb = lds_read8(Vt, nt2 * 16 + cl, kc * 4 + g4);
        o[nt2] = __builtin_amdgcn_mfma_f32_16x16x32_bf16(pa, vb, o[nt2], 0, 0, 0);
      }
    }
  }

  // epilogue: normalize, write CTX [b][s][h*64+e] bf16
  const int bb = bh >> 4, hh = bh & 15;
#pragma unroll
  for (int r = 0; r < 4; ++r) {
    float inv = 1.0f / ls[r];
    int row = q0 + w * 16 + g4 * 4 + r;
#pragma unroll
    for (int nt2 = 0; nt2 < 4; ++nt2) {
      CTX[(size_t)(bb * 2048 + row) * 1024 + hh * 64 + nt2 * 16 + cl] = (bf16)(o[nt2][r] * inv);
    }
  }
}

// ---------------- kernel 5: output projection + bias ----------------
// out[8192][1024] f32 = CTX bf16 @ Wo^T + bo ; B^T = WoB [n][d]

__launch_bounds__(256, 2)
__global__ void k_oproj(const bf16* __restrict__ X, const bf16* __restrict__ Wb,
                        const float* __restrict__ bo, float* __restrict__ out) {
  __shared__ __align__(16) bf16 As[128 * 64];
  __shared__ __align__(16) bf16 Bs[128 * 64];
  const int m0 = blockIdx.x * 128, n0 = blockIdx.y * 128;
  const int tid = threadIdx.x, w = tid >> 6, lane = tid & 63;
  const int wm = w >> 1, wn = w & 1;
  const int cl = lane & 15, g4 = lane >> 4;
  const int srow = lane >> 3;
  const int scol = ((lane & 7) ^ (lane >> 3)) << 3;
  f32x4 zero = {0.f, 0.f, 0.f, 0.f};
  f32x4 acc[4][4];
#pragma unroll
  for (int m = 0; m < 4; ++m)
#pragma unroll
    for (int n = 0; n < 4; ++n) acc[m][n] = zero;

  for (int kt = 0; kt < 16; ++kt) {
    const int k0 = kt * 64;
    __syncthreads();
#pragma unroll
    for (int c = 0; c < 4; ++c) {
      int cc = w * 4 + c;
      gload16(X + (size_t)(m0 + cc * 8 + srow) * 1024 + k0 + scol, (char*)As + cc * 1024);
      gload16(Wb + (size_t)(n0 + cc * 8 + srow) * 1024 + k0 + scol, (char*)Bs + cc * 1024);
    }
    __syncthreads();
#pragma unroll
    for (int kk = 0; kk < 2; ++kk) {
      bf16x8 a[4], b[4];
#pragma unroll
      for (int m = 0; m < 4; ++m) a[m] = lds_read8(As, wm * 64 + m * 16 + cl, kk * 4 + g4);
#pragma unroll
      for (int n = 0; n < 4; ++n) b[n] = lds_read8(Bs, wn * 64 + n * 16 + cl, kk * 4 + g4);
#pragma unroll
      for (int m = 0; m < 4; ++m)
#pragma unroll
        for (int n = 0; n < 4; ++n)
          acc[m][n] = __builtin_amdgcn_mfma_f32_16x16x32_bf16(a[m], b[n], acc[m][n], 0, 0, 0);
    }
  }
#pragma unroll
  for (int n = 0; n < 4; ++n) {
    int col = n0 + wn * 64 + n * 16 + cl;
    float bias = bo[col];
#pragma unroll
    for (int m = 0; m < 4; ++m)
#pragma unroll
      for (int r = 0; r < 4; ++r) {
        int row = m0 + wm * 64 + m * 16 + g4 * 4 + r;
        out[(size_t)row * 1024 + col] = acc[m][n][r] + bias;
      }
  }
}

// ---------------- launch ----------------

extern "C" void kernel_launch(void* const* d_in, const int* in_sizes, int n_in,
                              void* d_out, int out_size, void* d_ws, size_t ws_size,
                              hipStream_t stream) {
  const float* emb = (const float*)d_in[0];
  const float* Wq  = (const float*)d_in[1];
  const float* Wk  = (const float*)d_in[2];
  const float* Wv  = (const float*)d_in[3];
  const float* Wo  = (const float*)d_in[4];
  const float* bo  = (const float*)d_in[5];
  float* out = (float*)d_out;

  const size_t NEED = (size_t)72 << 20;
  if (ws_size < NEED) return;   // loud failure: output stays poisoned

  char* ws = (char*)d_ws;
  bf16* E   = (bf16*)(ws);                      // 16 MiB (reused as CTX later)
  bf16* WT  = (bf16*)(ws + ((size_t)16 << 20)); // 6 MiB
  bf16* WoB = (bf16*)(ws + ((size_t)22 << 20)); // 2 MiB
  bf16* Qw  = (bf16*)(ws + ((size_t)24 << 20)); // 16 MiB
  bf16* Kw  = (bf16*)(ws + ((size_t)40 << 20)); // 16 MiB
  bf16* Vw  = (bf16*)(ws + ((size_t)56 << 20)); // 16 MiB
  bf16* CTX = E;                                // E dead after k_qkv

  k_cvt_embed<<<4096, 256, 0, stream>>>(emb, E);
  k_cvt_w<<<16384, 256, 0, stream>>>(Wq, Wk, Wv, Wo, WT, WoB);
  k_qkv<<<dim3(64, 16), 256, 0, stream>>>(E, WT, Qw, Kw, Vw);
  k_attn<<<dim3(32, 64), 256, 0, stream>>>(Qw, Kw, Vw, CTX);
  k_oproj<<<dim3(64, 8), 256, 0, stream>>>(CTX, WoB, bo, out);
}

// Round 3
// 256.469 us; speedup vs baseline: 1.3933x; 1.3933x over previous
//
#include <hip/hip_runtime.h>
#include <hip/hip_bf16.h>
#include <stdint.h>
#include <stddef.h>

typedef __bf16 bf16;
typedef __bf16 bf16x8 __attribute__((ext_vector_type(8)));
typedef float f32x4 __attribute__((ext_vector_type(4)));
typedef float f32x16 __attribute__((ext_vector_type(16)));

// ---------------- helpers ----------------

__device__ __forceinline__ void gload16(const void* g, void* lds) {
  __builtin_amdgcn_global_load_lds(
      (const __attribute__((address_space(1))) unsigned int*)(uintptr_t)g,
      (__attribute__((address_space(3))) unsigned int*)(unsigned int)(uintptr_t)lds,
      16, 0, 0);
}

// rows are 64 bf16 = 128B. slot = 16B chunk index [0,8). XOR-swizzled.
__device__ __forceinline__ bf16x8 lds_read8(const bf16* base, int row, int slot) {
  const char* p = (const char*)base + row * 128 + ((slot ^ (row & 7)) << 4);
  return *(const bf16x8*)p;
}

// ---------------- kernel 1: embedded fp32 -> bf16 ----------------

__global__ void k_cvt_embed(const float* __restrict__ src, bf16* __restrict__ dst) {
  int i = blockIdx.x * blockDim.x + threadIdx.x;
  const float4* s4 = (const float4*)src;
  float4 a = s4[2 * i], b = s4[2 * i + 1];
  bf16x8 v;
  v[0] = (bf16)a.x; v[1] = (bf16)a.y; v[2] = (bf16)a.z; v[3] = (bf16)a.w;
  v[4] = (bf16)b.x; v[5] = (bf16)b.y; v[6] = (bf16)b.z; v[7] = (bf16)b.w;
  ((bf16x8*)dst)[i] = v;
}

// ---------------- kernel 2: weights -> bf16 (QKV transposed to B^T) --------

__global__ void k_cvt_w(const float* __restrict__ Wq, const float* __restrict__ Wk,
                        const float* __restrict__ Wv, const float* __restrict__ Wo,
                        bf16* __restrict__ WT, bf16* __restrict__ WoB) {
  int i = blockIdx.x * blockDim.x + threadIdx.x;
  if (i < 16 * 192 * 1024) {
    int h = i / (192 * 1024);
    int rem = i - h * (192 * 1024);
    int r = rem >> 10;
    int d = rem & 1023;
    const float* W = (r < 64) ? Wq : (r < 128 ? Wk : Wv);
    int e = r & 63;
    WT[i] = (bf16)W[h * 65536 + d * 64 + e];
  } else {
    int j = i - 16 * 192 * 1024;
    WoB[j] = (bf16)Wo[j];
  }
}

// ---------------- kernel 3: QKV projection GEMM ----------------

__launch_bounds__(256, 2)
__global__ void k_qkv(const bf16* __restrict__ E, const bf16* __restrict__ WT,
                      bf16* __restrict__ Qo, bf16* __restrict__ Ko, bf16* __restrict__ Vo) {
  __shared__ __align__(16) bf16 As[128 * 64];
  __shared__ __align__(16) bf16 Bs[192 * 64];
  const int h = blockIdx.y;
  const int m0 = blockIdx.x * 128;
  const int tid = threadIdx.x;
  const int w = tid >> 6, lane = tid & 63;
  const int wm = w >> 1, wn = w & 1;
  const int cl = lane & 15, g4 = lane >> 4;
  const int srow = lane >> 3;
  const int scol = ((lane & 7) ^ (lane >> 3)) << 3;
  const bf16* Wh = WT + (size_t)h * 192 * 1024;
  f32x4 zero = {0.f, 0.f, 0.f, 0.f};
  f32x4 acc[4][6];
#pragma unroll
  for (int m = 0; m < 4; ++m)
#pragma unroll
    for (int n = 0; n < 6; ++n) acc[m][n] = zero;

  for (int kt = 0; kt < 16; ++kt) {
    const int k0 = kt * 64;
    __syncthreads();
#pragma unroll
    for (int c = 0; c < 4; ++c) {
      int cc = w * 4 + c;
      gload16(E + (size_t)(m0 + cc * 8 + srow) * 1024 + k0 + scol, (char*)As + cc * 1024);
    }
#pragma unroll
    for (int c = 0; c < 6; ++c) {
      int cc = w * 6 + c;
      gload16(Wh + (size_t)(cc * 8 + srow) * 1024 + k0 + scol, (char*)Bs + cc * 1024);
    }
    __syncthreads();
#pragma unroll
    for (int kk = 0; kk < 2; ++kk) {
      bf16x8 a[4], b[6];
#pragma unroll
      for (int m = 0; m < 4; ++m) a[m] = lds_read8(As, wm * 64 + m * 16 + cl, kk * 4 + g4);
#pragma unroll
      for (int n = 0; n < 6; ++n) b[n] = lds_read8(Bs, wn * 96 + n * 16 + cl, kk * 4 + g4);
#pragma unroll
      for (int m = 0; m < 4; ++m)
#pragma unroll
        for (int n = 0; n < 6; ++n)
          acc[m][n] = __builtin_amdgcn_mfma_f32_16x16x32_bf16(a[m], b[n], acc[m][n], 0, 0, 0);
    }
  }
#pragma unroll
  for (int n = 0; n < 6; ++n) {
    int ncol = wn * 96 + n * 16 + cl;
    int which = ncol >> 6, e = ncol & 63;
    bf16* dst = which == 0 ? Qo : (which == 1 ? Ko : Vo);
#pragma unroll
    for (int m = 0; m < 4; ++m) {
#pragma unroll
      for (int r = 0; r < 4; ++r) {
        int row = m0 + wm * 64 + m * 16 + g4 * 4 + r;
        int bb = row >> 11, ss = row & 2047;
        dst[(((size_t)(bb * 16 + h) * 2048 + ss) << 6) + e] = (bf16)acc[m][n][r];
      }
    }
  }
}

// ---------------- kernel 4: causal flash attention (8-warp, 32x32, swapped) --
// grid (8 q-tiles of 256, 64 bh); 512 thr; warp w owns q-rows q0+32w..+31.
// Swapped QK^T: S^T = mfma(K,Q) -> lane holds P[q=lane&31][32 keys] in regs.
// Swapped PV:  O^T = mfma(V^T,P).  V^T columns stored permuted by
// phi(key)=swap bits2<->3, which makes the PV B-fragment exactly p[ks*8+j]
// (lane-local, no cross-lane exchange needed).

__launch_bounds__(512)
__global__ void k_attn(const bf16* __restrict__ Qg, const bf16* __restrict__ Kg,
                       const bf16* __restrict__ Vg, bf16* __restrict__ CTX) {
  __shared__ __align__(16) bf16 KS[2][4096];   // [key][d] 64x64, XOR-swizzled
  __shared__ __align__(16) bf16 VT[2][4096];   // [d][phi(key)] 64x64, XOR-swizzled
  const int qt = 7 - blockIdx.x;               // big blocks dispatch first
  const int bh = blockIdx.y;
  const int q0 = qt * 256;
  const int tid = threadIdx.x, w = tid >> 6, lane = tid & 63;
  const int ql = lane & 31, hi = lane >> 5;
  const int q = q0 + 32 * w + ql;
  const int qmin = q0 + 32 * w;
  const int qmax = qmin + 31;
  const bf16* Qb = Qg + (size_t)bh * (2048 * 64);
  const bf16* Kb = Kg + (size_t)bh * (2048 * 64);
  const bf16* Vb = Vg + (size_t)bh * (2048 * 64);
  const float CSC = 0.125f * 1.44269504089f;   // 1/sqrt(64) * log2(e)
  const int nkv = 4 * qt + 4;

  // Q fragments: qf[ks][j] = Q[q][ks*16 + 8*hi + j]
  bf16x8 qf[4];
#pragma unroll
  for (int ks = 0; ks < 4; ++ks)
    qf[ks] = *(const bf16x8*)(Qb + (size_t)q * 64 + ks * 16 + hi * 8);

  f32x16 o0, o1;
#pragma unroll
  for (int i = 0; i < 16; ++i) { o0[i] = 0.f; o1[i] = 0.f; }
  float mr = -1e30f, ls = 0.f;

  // staging geometry
  const int srowK = w * 8 + (lane >> 3);
  const int scolK = ((lane & 7) ^ ((lane >> 3) & 7)) << 3;   // pre-swizzled src col
  const int lanep = (lane & ~12) | ((lane & 4) << 1) | ((lane & 8) >> 1);  // phi(lane)
  int offs[4];
#pragma unroll
  for (int ks = 0; ks < 4; ++ks) offs[ks] = (ks * 32 + hi * 16) ^ ((ql & 7) << 4);

  // prologue: stage tile 0 into buf 0
  {
    gload16(Kb + (size_t)srowK * 64 + scolK, (char*)KS[0] + w * 1024);
    bf16x8 v = *(const bf16x8*)(Vb + (size_t)lane * 64 + w * 8);
#pragma unroll
    for (int j = 0; j < 8; ++j)
      *(bf16*)((char*)VT[0] + w * 1024 + j * 128 + ((lanep * 2) ^ (j << 4))) = v[j];
  }

  int cur = 0;
  for (int t = 0; t < nkv; ++t) {
    const int kv0 = t * 64;
    __syncthreads();                              // buf[cur] ready; buf[cur^1] free
    bf16x8 vnext;
    const bool more = (t + 1 < nkv);
    if (more) {
      const int kn = kv0 + 64;
      vnext = *(const bf16x8*)(Vb + (size_t)(kn + lane) * 64 + w * 8);   // issue early
      gload16(Kb + (size_t)(kn + srowK) * 64 + scolK, (char*)KS[cur ^ 1] + w * 1024);
    }
    const bool active = (kv0 <= qmax);
    float p[32];
    if (active) {
      // ---- QK^T ----
      f32x16 s0, s1;
#pragma unroll
      for (int i = 0; i < 16; ++i) { s0[i] = 0.f; s1[i] = 0.f; }
      const char* kbase = (const char*)KS[cur];
#pragma unroll
      for (int ks = 0; ks < 4; ++ks) {
        bf16x8 k0 = *(const bf16x8*)(kbase + ql * 128 + offs[ks]);
        bf16x8 k1 = *(const bf16x8*)(kbase + (32 + ql) * 128 + offs[ks]);
        s0 = __builtin_amdgcn_mfma_f32_32x32x16_bf16(k0, qf[ks], s0, 0, 0, 0);
        s1 = __builtin_amdgcn_mfma_f32_32x32x16_bf16(k1, qf[ks], s1, 0, 0, 0);
      }
      // ---- scale + causal mask ----
#pragma unroll
      for (int r = 0; r < 16; ++r) { p[r] = s0[r] * CSC; p[16 + r] = s1[r] * CSC; }
      if (kv0 + 63 > qmin) {
#pragma unroll
        for (int kb = 0; kb < 2; ++kb)
#pragma unroll
          for (int r = 0; r < 16; ++r) {
            int key = kv0 + kb * 32 + (r & 3) + 8 * (r >> 2) + 4 * hi;
            if (key > q) p[kb * 16 + r] = -1e30f;
          }
      }
      // ---- online softmax (lane-local row; cross-half via shfl_xor 32) ----
      float t8[8];
#pragma unroll
      for (int i = 0; i < 8; ++i)
        t8[i] = fmaxf(fmaxf(p[i], p[i + 8]), fmaxf(p[i + 16], p[i + 24]));
      float mA = fmaxf(fmaxf(t8[0], t8[1]), fmaxf(t8[2], t8[3]));
      float mB = fmaxf(fmaxf(t8[4], t8[5]), fmaxf(t8[6], t8[7]));
      float pmax = fmaxf(mA, mB);
      pmax = fmaxf(pmax, __shfl_xor(pmax, 32));
      if (__any(pmax - mr > 8.0f)) {              // defer-max (T13)
        float mnew = fmaxf(mr, pmax);
        float al = exp2f(mr - mnew);
        mr = mnew; ls *= al;
#pragma unroll
        for (int i = 0; i < 16; ++i) { o0[i] *= al; o1[i] *= al; }
      }
#pragma unroll
      for (int i = 0; i < 32; ++i) p[i] = exp2f(p[i] - mr);
      float a8[8];
#pragma unroll
      for (int i = 0; i < 8; ++i) a8[i] = (p[i] + p[i + 8]) + (p[i + 16] + p[i + 24]);
      float rs = (a8[0] + a8[1]) + (a8[2] + a8[3]) + (a8[4] + a8[5]) + (a8[6] + a8[7]);
      rs += __shfl_xor(rs, 32);
      ls += rs;
    }
    // ---- write next V tile (transposed, phi-permuted, swizzled) ----
    if (more) {
#pragma unroll
      for (int j = 0; j < 8; ++j)
        *(bf16*)((char*)VT[cur ^ 1] + w * 1024 + j * 128 + ((lanep * 2) ^ (j << 4))) = vnext[j];
    }
    if (active) {
      // ---- O^T += V^T P  (P fragment is lane-local: element j = p[ks*8+j]) ----
      const char* vbase = (const char*)VT[cur];
#pragma unroll
      for (int ks = 0; ks < 4; ++ks) {
        bf16x8 pf;
#pragma unroll
        for (int j = 0; j < 8; ++j) pf[j] = (bf16)p[ks * 8 + j];
        bf16x8 v0 = *(const bf16x8*)(vbase + ql * 128 + offs[ks]);
        bf16x8 v1 = *(const bf16x8*)(vbase + (32 + ql) * 128 + offs[ks]);
        o0 = __builtin_amdgcn_mfma_f32_32x32x16_bf16(v0, pf, o0, 0, 0, 0);
        o1 = __builtin_amdgcn_mfma_f32_32x32x16_bf16(v1, pf, o1, 0, 0, 0);
      }
    }
    cur ^= 1;
  }

  // epilogue: normalize, write CTX [b][s][h*64+d] bf16
  const float inv = 1.0f / ls;
  const int bb = bh >> 4, hh = bh & 15;
  bf16* Cp = CTX + ((size_t)(bb * 2048 + q) * 1024) + hh * 64;
#pragma unroll
  for (int r = 0; r < 16; ++r) {
    int d0 = (r & 3) + 8 * (r >> 2) + 4 * hi;
    Cp[d0] = (bf16)(o0[r] * inv);
    Cp[32 + d0] = (bf16)(o1[r] * inv);
  }
}

// ---------------- kernel 5: output projection + bias ----------------

__launch_bounds__(256, 2)
__global__ void k_oproj(const bf16* __restrict__ X, const bf16* __restrict__ Wb,
                        const float* __restrict__ bo, float* __restrict__ out) {
  __shared__ __align__(16) bf16 As[128 * 64];
  __shared__ __align__(16) bf16 Bs[128 * 64];
  const int m0 = blockIdx.x * 128, n0 = blockIdx.y * 128;
  const int tid = threadIdx.x, w = tid >> 6, lane = tid & 63;
  const int wm = w >> 1, wn = w & 1;
  const int cl = lane & 15, g4 = lane >> 4;
  const int srow = lane >> 3;
  const int scol = ((lane & 7) ^ (lane >> 3)) << 3;
  f32x4 zero = {0.f, 0.f, 0.f, 0.f};
  f32x4 acc[4][4];
#pragma unroll
  for (int m = 0; m < 4; ++m)
#pragma unroll
    for (int n = 0; n < 4; ++n) acc[m][n] = zero;

  for (int kt = 0; kt < 16; ++kt) {
    const int k0 = kt * 64;
    __syncthreads();
#pragma unroll
    for (int c = 0; c < 4; ++c) {
      int cc = w * 4 + c;
      gload16(X + (size_t)(m0 + cc * 8 + srow) * 1024 + k0 + scol, (char*)As + cc * 1024);
      gload16(Wb + (size_t)(n0 + cc * 8 + srow) * 1024 + k0 + scol, (char*)Bs + cc * 1024);
    }
    __syncthreads();
#pragma unroll
    for (int kk = 0; kk < 2; ++kk) {
      bf16x8 a[4], b[4];
#pragma unroll
      for (int m = 0; m < 4; ++m) a[m] = lds_read8(As, wm * 64 + m * 16 + cl, kk * 4 + g4);
#pragma unroll
      for (int n = 0; n < 4; ++n) b[n] = lds_read8(Bs, wn * 64 + n * 16 + cl, kk * 4 + g4);
#pragma unroll
      for (int m = 0; m < 4; ++m)
#pragma unroll
        for (int n = 0; n < 4; ++n)
          acc[m][n] = __builtin_amdgcn_mfma_f32_16x16x32_bf16(a[m], b[n], acc[m][n], 0, 0, 0);
    }
  }
#pragma unroll
  for (int n = 0; n < 4; ++n) {
    int col = n0 + wn * 64 + n * 16 + cl;
    float bias = bo[col];
#pragma unroll
    for (int m = 0; m < 4; ++m)
#pragma unroll
      for (int r = 0; r < 4; ++r) {
        int row = m0 + wm * 64 + m * 16 + g4 * 4 + r;
        out[(size_t)row * 1024 + col] = acc[m][n][r] + bias;
      }
  }
}

// ---------------- launch ----------------

extern "C" void kernel_launch(void* const* d_in, const int* in_sizes, int n_in,
                              void* d_out, int out_size, void* d_ws, size_t ws_size,
                              hipStream_t stream) {
  const float* emb = (const float*)d_in[0];
  const float* Wq  = (const float*)d_in[1];
  const float* Wk  = (const float*)d_in[2];
  const float* Wv  = (const float*)d_in[3];
  const float* Wo  = (const float*)d_in[4];
  const float* bo  = (const float*)d_in[5];
  float* out = (float*)d_out;

  const size_t NEED = (size_t)72 << 20;
  if (ws_size < NEED) return;

  char* ws = (char*)d_ws;
  bf16* E   = (bf16*)(ws);
  bf16* WT  = (bf16*)(ws + ((size_t)16 << 20));
  bf16* WoB = (bf16*)(ws + ((size_t)22 << 20));
  bf16* Qw  = (bf16*)(ws + ((size_t)24 << 20));
  bf16* Kw  = (bf16*)(ws + ((size_t)40 << 20));
  bf16* Vw  = (bf16*)(ws + ((size_t)56 << 20));
  bf16* CTX = E;

  k_cvt_embed<<<4096, 256, 0, stream>>>(emb, E);
  k_cvt_w<<<16384, 256, 0, stream>>>(Wq, Wk, Wv, Wo, WT, WoB);
  k_qkv<<<dim3(64, 16), 256, 0, stream>>>(E, WT, Qw, Kw, Vw);
  k_attn<<<dim3(8, 64), 512, 0, stream>>>(Qw, Kw, Vw, CTX);
  k_oproj<<<dim3(64, 8), 256, 0, stream>>>(CTX, WoB, bo, out);
}

// Round 4
// 190.671 us; speedup vs baseline: 1.8741x; 1.3451x over previous
//
#include <hip/hip_runtime.h>
#include <hip/hip_bf16.h>
#include <stdint.h>
#include <stddef.h>

typedef __bf16 bf16;
typedef __bf16 bf16x8 __attribute__((ext_vector_type(8)));
typedef float f32x4 __attribute__((ext_vector_type(4)));
typedef float f32x16 __attribute__((ext_vector_type(16)));

// ---------------- helpers ----------------

__device__ __forceinline__ void gload16(const void* g, void* lds) {
  __builtin_amdgcn_global_load_lds(
      (const __attribute__((address_space(1))) unsigned int*)(uintptr_t)g,
      (__attribute__((address_space(3))) unsigned int*)(unsigned int)(uintptr_t)lds,
      16, 0, 0);
}

// rows are 64 bf16 = 128B. slot = 16B chunk index [0,8). XOR-swizzled.
__device__ __forceinline__ bf16x8 lds_read8(const bf16* base, int row, int slot) {
  const char* p = (const char*)base + row * 128 + ((slot ^ (row & 7)) << 4);
  return *(const bf16x8*)p;
}

// ---------------- kernel 1: embedded fp32 -> bf16 ----------------

__global__ void k_cvt_embed(const float* __restrict__ src, bf16* __restrict__ dst) {
  int i = blockIdx.x * blockDim.x + threadIdx.x;
  const float4* s4 = (const float4*)src;
  float4 a = s4[2 * i], b = s4[2 * i + 1];
  bf16x8 v;
  v[0] = (bf16)a.x; v[1] = (bf16)a.y; v[2] = (bf16)a.z; v[3] = (bf16)a.w;
  v[4] = (bf16)b.x; v[5] = (bf16)b.y; v[6] = (bf16)b.z; v[7] = (bf16)b.w;
  ((bf16x8*)dst)[i] = v;
}

// ---------------- kernel 2: weights -> bf16 (QKV transposed to B^T) --------

__global__ void k_cvt_w(const float* __restrict__ Wq, const float* __restrict__ Wk,
                        const float* __restrict__ Wv, const float* __restrict__ Wo,
                        bf16* __restrict__ WT, bf16* __restrict__ WoB) {
  int i = blockIdx.x * blockDim.x + threadIdx.x;
  if (i < 16 * 192 * 1024) {
    int h = i / (192 * 1024);
    int rem = i - h * (192 * 1024);
    int r = rem >> 10;
    int d = rem & 1023;
    const float* W = (r < 64) ? Wq : (r < 128 ? Wk : Wv);
    int e = r & 63;
    WT[i] = (bf16)W[h * 65536 + d * 64 + e];
  } else {
    int j = i - 16 * 192 * 1024;
    WoB[j] = (bf16)Wo[j];
  }
}

// ---------------- kernel 3: QKV projection GEMM ----------------
// Q columns are pre-scaled by 1/sqrt(64)*log2(e) (softmax scale folded in).

__launch_bounds__(256, 2)
__global__ void k_qkv(const bf16* __restrict__ E, const bf16* __restrict__ WT,
                      bf16* __restrict__ Qo, bf16* __restrict__ Ko, bf16* __restrict__ Vo) {
  __shared__ __align__(16) bf16 As[128 * 64];
  __shared__ __align__(16) bf16 Bs[192 * 64];
  const int h = blockIdx.y;
  const int m0 = blockIdx.x * 128;
  const int tid = threadIdx.x;
  const int w = tid >> 6, lane = tid & 63;
  const int wm = w >> 1, wn = w & 1;
  const int cl = lane & 15, g4 = lane >> 4;
  const int srow = lane >> 3;
  const int scol = ((lane & 7) ^ (lane >> 3)) << 3;
  const bf16* Wh = WT + (size_t)h * 192 * 1024;
  f32x4 zero = {0.f, 0.f, 0.f, 0.f};
  f32x4 acc[4][6];
#pragma unroll
  for (int m = 0; m < 4; ++m)
#pragma unroll
    for (int n = 0; n < 6; ++n) acc[m][n] = zero;

  for (int kt = 0; kt < 16; ++kt) {
    const int k0 = kt * 64;
    __syncthreads();
#pragma unroll
    for (int c = 0; c < 4; ++c) {
      int cc = w * 4 + c;
      gload16(E + (size_t)(m0 + cc * 8 + srow) * 1024 + k0 + scol, (char*)As + cc * 1024);
    }
#pragma unroll
    for (int c = 0; c < 6; ++c) {
      int cc = w * 6 + c;
      gload16(Wh + (size_t)(cc * 8 + srow) * 1024 + k0 + scol, (char*)Bs + cc * 1024);
    }
    __syncthreads();
#pragma unroll
    for (int kk = 0; kk < 2; ++kk) {
      bf16x8 a[4], b[6];
#pragma unroll
      for (int m = 0; m < 4; ++m) a[m] = lds_read8(As, wm * 64 + m * 16 + cl, kk * 4 + g4);
#pragma unroll
      for (int n = 0; n < 6; ++n) b[n] = lds_read8(Bs, wn * 96 + n * 16 + cl, kk * 4 + g4);
#pragma unroll
      for (int m = 0; m < 4; ++m)
#pragma unroll
        for (int n = 0; n < 6; ++n)
          acc[m][n] = __builtin_amdgcn_mfma_f32_16x16x32_bf16(a[m], b[n], acc[m][n], 0, 0, 0);
    }
  }
#pragma unroll
  for (int n = 0; n < 6; ++n) {
    int ncol = wn * 96 + n * 16 + cl;
    int which = ncol >> 6, e = ncol & 63;
    bf16* dst = which == 0 ? Qo : (which == 1 ? Ko : Vo);
    const float sc = (which == 0) ? 0.18033688f : 1.0f;   // 0.125 * log2(e)
#pragma unroll
    for (int m = 0; m < 4; ++m) {
#pragma unroll
      for (int r = 0; r < 4; ++r) {
        int row = m0 + wm * 64 + m * 16 + g4 * 4 + r;
        int bb = row >> 11, ss = row & 2047;
        dst[(((size_t)(bb * 16 + h) * 2048 + ss) << 6) + e] = (bf16)(acc[m][n][r] * sc);
      }
    }
  }
}

// ---------------- kernel 4: causal flash attention (8-warp, 32x32, swapped) --
// 1D grid 512: bh = b&63, t = b>>6, qt = t<4 ? t : 11-t.
//  -> XCD (=b%8=bh%8) sees all qt equally; CU pairs (b, b+256) get
//     complementary tiles (work sums to 36 iters on every CU).
// Swapped QK^T: S^T = mfma(K,Q) -> lane holds P[q=lane&31][32 keys] in regs.
// Swapped PV:  O^T = mfma(V^T,P).  V^T columns stored permuted by
// phi(key)=swap bits2<->3 -> PV B-fragment is lane-local p[ks*8+j].

__launch_bounds__(512)
__global__ void k_attn(const bf16* __restrict__ Qg, const bf16* __restrict__ Kg,
                       const bf16* __restrict__ Vg, bf16* __restrict__ CTX) {
  __shared__ __align__(16) bf16 KS[2][4096];   // [key][d] 64x64, XOR-swizzled
  __shared__ __align__(16) bf16 VT[2][4096];   // [d][phi(key)] 64x64, XOR-swizzled
  const int b = blockIdx.x;
  const int bh = b & 63;
  const int t6 = b >> 6;
  const int qt = (t6 < 4) ? t6 : 11 - t6;
  const int q0 = qt * 256;
  const int tid = threadIdx.x, w = tid >> 6, lane = tid & 63;
  const int ql = lane & 31, hi = lane >> 5;
  const int q = q0 + 32 * w + ql;
  const int qmin = q0 + 32 * w;
  const int qmax = qmin + 31;
  const bf16* Qb = Qg + (size_t)bh * (2048 * 64);
  const bf16* Kb = Kg + (size_t)bh * (2048 * 64);
  const bf16* Vb = Vg + (size_t)bh * (2048 * 64);
  const int nkv = 4 * qt + 4;

  // Q fragments: qf[ks][j] = Q[q][ks*16 + 8*hi + j]  (pre-scaled in k_qkv)
  bf16x8 qf[4];
#pragma unroll
  for (int ks = 0; ks < 4; ++ks)
    qf[ks] = *(const bf16x8*)(Qb + (size_t)q * 64 + ks * 16 + hi * 8);

  f32x16 o0, o1;
#pragma unroll
  for (int i = 0; i < 16; ++i) { o0[i] = 0.f; o1[i] = 0.f; }
  float mr = -1e30f, ls = 0.f;

  // staging geometry
  const int srowK = w * 8 + (lane >> 3);
  const int scolK = ((lane & 7) ^ ((lane >> 3) & 7)) << 3;   // pre-swizzled src col
  const int lanep = (lane & ~12) | ((lane & 4) << 1) | ((lane & 8) >> 1);  // phi(lane)
  int offs[4];
#pragma unroll
  for (int ks = 0; ks < 4; ++ks) offs[ks] = (ks * 32 + hi * 16) ^ ((ql & 7) << 4);

  // prologue: stage tile 0 into buf 0
  {
    gload16(Kb + (size_t)srowK * 64 + scolK, (char*)KS[0] + w * 1024);
    bf16x8 v = *(const bf16x8*)(Vb + (size_t)lane * 64 + w * 8);
#pragma unroll
    for (int j = 0; j < 8; ++j)
      *(bf16*)((char*)VT[0] + w * 1024 + j * 128 + ((lanep * 2) ^ (j << 4))) = v[j];
  }

  int cur = 0;
  for (int t = 0; t < nkv; ++t) {
    const int kv0 = t * 64;
    __syncthreads();                              // buf[cur] ready; buf[cur^1] free
    bf16x8 vnext;
    const bool more = (t + 1 < nkv);
    if (more) {
      const int kn = kv0 + 64;
      vnext = *(const bf16x8*)(Vb + (size_t)(kn + lane) * 64 + w * 8);   // issue early
      gload16(Kb + (size_t)(kn + srowK) * 64 + scolK, (char*)KS[cur ^ 1] + w * 1024);
    }
    const bool active = (kv0 <= qmax);
    float p[32];
    if (active) {
      // ---- QK^T ----
      f32x16 s0, s1;
#pragma unroll
      for (int i = 0; i < 16; ++i) { s0[i] = 0.f; s1[i] = 0.f; }
      const char* kbase = (const char*)KS[cur];
      __builtin_amdgcn_s_setprio(1);
#pragma unroll
      for (int ks = 0; ks < 4; ++ks) {
        bf16x8 k0 = *(const bf16x8*)(kbase + ql * 128 + offs[ks]);
        bf16x8 k1 = *(const bf16x8*)(kbase + (32 + ql) * 128 + offs[ks]);
        s0 = __builtin_amdgcn_mfma_f32_32x32x16_bf16(k0, qf[ks], s0, 0, 0, 0);
        s1 = __builtin_amdgcn_mfma_f32_32x32x16_bf16(k1, qf[ks], s1, 0, 0, 0);
      }
      __builtin_amdgcn_s_setprio(0);
      // ---- causal mask (scale pre-folded into Q) ----
#pragma unroll
      for (int r = 0; r < 16; ++r) { p[r] = s0[r]; p[16 + r] = s1[r]; }
      if (kv0 + 63 > qmin) {
#pragma unroll
        for (int kb = 0; kb < 2; ++kb)
#pragma unroll
          for (int r = 0; r < 16; ++r) {
            int key = kv0 + kb * 32 + (r & 3) + 8 * (r >> 2) + 4 * hi;
            if (key > q) p[kb * 16 + r] = -1e30f;
          }
      }
      // ---- online softmax (lane-local row; cross-half via shfl_xor 32) ----
      float t8[8];
#pragma unroll
      for (int i = 0; i < 8; ++i)
        t8[i] = fmaxf(fmaxf(fmaxf(p[i], p[i + 8]), p[i + 16]), p[i + 24]);
      float mA = fmaxf(fmaxf(t8[0], t8[1]), fmaxf(t8[2], t8[3]));
      float mB = fmaxf(fmaxf(t8[4], t8[5]), fmaxf(t8[6], t8[7]));
      float pmax = fmaxf(mA, mB);
      pmax = fmaxf(pmax, __shfl_xor(pmax, 32));
      if (__any(pmax - mr > 8.0f)) {              // defer-max (T13)
        float mnew = fmaxf(mr, pmax);
        float al = exp2f(mr - mnew);
        mr = mnew; ls *= al;
#pragma unroll
        for (int i = 0; i < 16; ++i) { o0[i] *= al; o1[i] *= al; }
      }
#pragma unroll
      for (int i = 0; i < 32; ++i) p[i] = exp2f(p[i] - mr);
      float a8[8];
#pragma unroll
      for (int i = 0; i < 8; ++i) a8[i] = (p[i] + p[i + 8]) + (p[i + 16] + p[i + 24]);
      float rs = (a8[0] + a8[1]) + (a8[2] + a8[3]) + (a8[4] + a8[5]) + (a8[6] + a8[7]);
      rs += __shfl_xor(rs, 32);
      ls += rs;
    }
    // ---- write next V tile (transposed, phi-permuted, swizzled) ----
    if (more) {
#pragma unroll
      for (int j = 0; j < 8; ++j)
        *(bf16*)((char*)VT[cur ^ 1] + w * 1024 + j * 128 + ((lanep * 2) ^ (j << 4))) = vnext[j];
    }
    if (active) {
      // ---- O^T += V^T P  (P fragment is lane-local: element j = p[ks*8+j]) ----
      const char* vbase = (const char*)VT[cur];
      __builtin_amdgcn_s_setprio(1);
#pragma unroll
      for (int ks = 0; ks < 4; ++ks) {
        bf16x8 pf;
#pragma unroll
        for (int j = 0; j < 8; ++j) pf[j] = (bf16)p[ks * 8 + j];
        bf16x8 v0 = *(const bf16x8*)(vbase + ql * 128 + offs[ks]);
        bf16x8 v1 = *(const bf16x8*)(vbase + (32 + ql) * 128 + offs[ks]);
        o0 = __builtin_amdgcn_mfma_f32_32x32x16_bf16(v0, pf, o0, 0, 0, 0);
        o1 = __builtin_amdgcn_mfma_f32_32x32x16_bf16(v1, pf, o1, 0, 0, 0);
      }
      __builtin_amdgcn_s_setprio(0);
    }
    cur ^= 1;
  }

  // epilogue: normalize, write CTX [b][s][h*64+d] bf16
  const float inv = 1.0f / ls;
  const int bb = bh >> 4, hh = bh & 15;
  bf16* Cp = CTX + ((size_t)(bb * 2048 + q) * 1024) + hh * 64;
#pragma unroll
  for (int r = 0; r < 16; ++r) {
    int d0 = (r & 3) + 8 * (r >> 2) + 4 * hi;
    Cp[d0] = (bf16)(o0[r] * inv);
    Cp[32 + d0] = (bf16)(o1[r] * inv);
  }
}

// ---------------- kernel 5: output projection + bias ----------------

__launch_bounds__(256, 2)
__global__ void k_oproj(const bf16* __restrict__ X, const bf16* __restrict__ Wb,
                        const float* __restrict__ bo, float* __restrict__ out) {
  __shared__ __align__(16) bf16 As[128 * 64];
  __shared__ __align__(16) bf16 Bs[128 * 64];
  const int m0 = blockIdx.x * 128, n0 = blockIdx.y * 128;
  const int tid = threadIdx.x, w = tid >> 6, lane = tid & 63;
  const int wm = w >> 1, wn = w & 1;
  const int cl = lane & 15, g4 = lane >> 4;
  const int srow = lane >> 3;
  const int scol = ((lane & 7) ^ (lane >> 3)) << 3;
  f32x4 zero = {0.f, 0.f, 0.f, 0.f};
  f32x4 acc[4][4];
#pragma unroll
  for (int m = 0; m < 4; ++m)
#pragma unroll
    for (int n = 0; n < 4; ++n) acc[m][n] = zero;

  for (int kt = 0; kt < 16; ++kt) {
    const int k0 = kt * 64;
    __syncthreads();
#pragma unroll
    for (int c = 0; c < 4; ++c) {
      int cc = w * 4 + c;
      gload16(X + (size_t)(m0 + cc * 8 + srow) * 1024 + k0 + scol, (char*)As + cc * 1024);
      gload16(Wb + (size_t)(n0 + cc * 8 + srow) * 1024 + k0 + scol, (char*)Bs + cc * 1024);
    }
    __syncthreads();
#pragma unroll
    for (int kk = 0; kk < 2; ++kk) {
      bf16x8 a[4], b[4];
#pragma unroll
      for (int m = 0; m < 4; ++m) a[m] = lds_read8(As, wm * 64 + m * 16 + cl, kk * 4 + g4);
#pragma unroll
      for (int n = 0; n < 4; ++n) b[n] = lds_read8(Bs, wn * 64 + n * 16 + cl, kk * 4 + g4);
#pragma unroll
      for (int m = 0; m < 4; ++m)
#pragma unroll
        for (int n = 0; n < 4; ++n)
          acc[m][n] = __builtin_amdgcn_mfma_f32_16x16x32_bf16(a[m], b[n], acc[m][n], 0, 0, 0);
    }
  }
#pragma unroll
  for (int n = 0; n < 4; ++n) {
    int col = n0 + wn * 64 + n * 16 + cl;
    float bias = bo[col];
#pragma unroll
    for (int m = 0; m < 4; ++m)
#pragma unroll
      for (int r = 0; r < 4; ++r) {
        int row = m0 + wm * 64 + m * 16 + g4 * 4 + r;
        out[(size_t)row * 1024 + col] = acc[m][n][r] + bias;
      }
  }
}

// ---------------- launch ----------------

extern "C" void kernel_launch(void* const* d_in, const int* in_sizes, int n_in,
                              void* d_out, int out_size, void* d_ws, size_t ws_size,
                              hipStream_t stream) {
  const float* emb = (const float*)d_in[0];
  const float* Wq  = (const float*)d_in[1];
  const float* Wk  = (const float*)d_in[2];
  const float* Wv  = (const float*)d_in[3];
  const float* Wo  = (const float*)d_in[4];
  const float* bo  = (const float*)d_in[5];
  float* out = (float*)d_out;

  const size_t NEED = (size_t)72 << 20;
  if (ws_size < NEED) return;

  char* ws = (char*)d_ws;
  bf16* E   = (bf16*)(ws);
  bf16* WT  = (bf16*)(ws + ((size_t)16 << 20));
  bf16* WoB = (bf16*)(ws + ((size_t)22 << 20));
  bf16* Qw  = (bf16*)(ws + ((size_t)24 << 20));
  bf16* Kw  = (bf16*)(ws + ((size_t)40 << 20));
  bf16* Vw  = (bf16*)(ws + ((size_t)56 << 20));
  bf16* CTX = E;

  k_cvt_embed<<<4096, 256, 0, stream>>>(emb, E);
  k_cvt_w<<<16384, 256, 0, stream>>>(Wq, Wk, Wv, Wo, WT, WoB);
  k_qkv<<<dim3(64, 16), 256, 0, stream>>>(E, WT, Qw, Kw, Vw);
  k_attn<<<512, 512, 0, stream>>>(Qw, Kw, Vw, CTX);
  k_oproj<<<dim3(64, 8), 256, 0, stream>>>(CTX, WoB, bo, out);
}